// Round 1
// baseline (161.427 us; speedup 1.0000x reference)
//
#include <hip/hip_runtime.h>
#include <hip/hip_bf16.h>

// NLinear: out[b,f,o] = sum_i x[b,f,i] * w[f,i,o] + bias[f,o]
// B=8192, F=64, I=128, O=128, all fp32.
// Memory-bound (540MB traffic, 17.2 GFLOP). bf16 MFMA to stay under roofline.

#define BATCH 8192
#define NF 64
#define DI 128
#define DO 128
#define BM 128           // rows per tile
#define TILES_PER_BLOCK 4
#define CHUNKS (BATCH / BM / TILES_PER_BLOCK)   // 16 chunks per feature

typedef __attribute__((ext_vector_type(8))) short short8;
typedef __attribute__((ext_vector_type(4))) float floatx4;

// round-to-nearest-even f32 -> bf16 bits
static __device__ __forceinline__ unsigned short f2bf(float f) {
    union { float f; unsigned u; } v; v.f = f;
    unsigned r = v.u + 0x7fffu + ((v.u >> 16) & 1u);
    return (unsigned short)(r >> 16);
}

__global__ __launch_bounds__(256, 2)
void nlinear_kernel(const float* __restrict__ x,
                    const float* __restrict__ w,
                    const float* __restrict__ bias,
                    float* __restrict__ out) {
    // 32KB each, bf16, XOR-swizzled layout: byte = row*256 + (colbyte ^ ((row&7)<<4))
    __shared__ unsigned short lds_x[BM * DI];    // X tile   [row][k]
    __shared__ unsigned short lds_wt[DO * DI];   // W^T      [o][k]
    __shared__ float lds_bias[DO];

    // Bijective XCD swizzle (grid=1024, 1024%8==0): all 16 chunks of a feature
    // land on one XCD -> W_f stays resident in that XCD's L2.
    int b = blockIdx.x;
    int logical = (b & 7) * (CHUNKS * NF / 8) + (b >> 3);
    int f = logical >> 4;          // 0..63
    int chunk = logical & 15;      // 0..15

    int tid  = threadIdx.x;
    int lane = tid & 63;
    int wid  = tid >> 6;           // 0..3

    // ---- stage W^T (bf16, swizzled) once per block ----
    const float* wf = w + (size_t)f * DI * DO;
    #pragma unroll 4
    for (int it = 0; it < 16; ++it) {
        int id = it * 256 + tid;
        int i  = id >> 5;             // input dim 0..127
        int o4 = (id & 31) << 2;      // output dim group
        floatx4 v = *(const floatx4*)(wf + i * DO + o4);
        #pragma unroll
        for (int j = 0; j < 4; ++j) {
            int o = o4 + j;
            int byte = o * 256 + ((i * 2) ^ ((o & 7) << 4));
            *(unsigned short*)((char*)lds_wt + byte) = f2bf(v[j]);
        }
    }
    if (tid < DO) lds_bias[tid] = bias[f * DO + tid];

    for (int t = 0; t < TILES_PER_BLOCK; ++t) {
        int row0 = (chunk * TILES_PER_BLOCK + t) * BM;

        __syncthreads();   // protect lds_x from prev compute / cover wt+bias on t=0

        // ---- stage X tile: 128 rows x 128 k, f32 -> bf16, swizzled ----
        #pragma unroll 8
        for (int it = 0; it < 16; ++it) {
            int id = it * 256 + tid;
            int r  = id >> 5;             // 0..127
            int c4 = (id & 31) << 2;      // k group (floats)
            const float* xp = x + (size_t)(row0 + r) * (NF * DI) + f * DI + c4;
            floatx4 v = *(const floatx4*)xp;
            ushort4 pk;
            pk.x = f2bf(v[0]); pk.y = f2bf(v[1]);
            pk.z = f2bf(v[2]); pk.w = f2bf(v[3]);
            int byte = r * 256 + ((c4 * 2) ^ ((r & 7) << 4));
            *(ushort4*)((char*)lds_x + byte) = pk;
        }

        __syncthreads();

        // ---- MFMA: wave wid owns rows wid*32..+31, all 128 cols ----
        floatx4 acc[2][8];
        #pragma unroll
        for (int m = 0; m < 2; ++m)
            #pragma unroll
            for (int n = 0; n < 8; ++n)
                acc[m][n] = (floatx4){0.f, 0.f, 0.f, 0.f};

        int lrow = lane & 15;
        int lk16 = (lane >> 4) * 16;   // byte offset of this lane's k-subgroup

        #pragma unroll
        for (int kk = 0; kk < 4; ++kk) {
            int kbyte = kk * 64 + lk16;
            short8 a[2], bf[8];
            #pragma unroll
            for (int m = 0; m < 2; ++m) {
                int r = wid * 32 + m * 16 + lrow;
                a[m] = *(const short8*)((const char*)lds_x +
                        r * 256 + (kbyte ^ ((r & 7) << 4)));
            }
            #pragma unroll
            for (int n = 0; n < 8; ++n) {
                int o = n * 16 + lrow;
                bf[n] = *(const short8*)((const char*)lds_wt +
                        o * 256 + (kbyte ^ ((o & 7) << 4)));
            }
            #pragma unroll
            for (int m = 0; m < 2; ++m)
                #pragma unroll
                for (int n = 0; n < 8; ++n)
                    acc[m][n] = __builtin_amdgcn_mfma_f32_16x16x32_bf16(
                        a[m], bf[n], acc[m][n], 0, 0, 0);
        }

        // ---- epilogue: C row=(lane>>4)*4+j, col=lane&15 (m89-verified) ----
        int col0 = lane & 15;
        int rgrp = lane >> 4;
        #pragma unroll
        for (int m = 0; m < 2; ++m) {
            int rbase = row0 + wid * 32 + m * 16 + rgrp * 4;
            #pragma unroll
            for (int n = 0; n < 8; ++n) {
                int o = n * 16 + col0;
                float bv = lds_bias[o];
                #pragma unroll
                for (int j = 0; j < 4; ++j) {
                    out[(size_t)(rbase + j) * (NF * DO) + f * DO + o] =
                        acc[m][n][j] + bv;
                }
            }
        }
    }
}

extern "C" void kernel_launch(void* const* d_in, const int* in_sizes, int n_in,
                              void* d_out, int out_size, void* d_ws, size_t ws_size,
                              hipStream_t stream) {
    const float* x    = (const float*)d_in[0];
    const float* wght = (const float*)d_in[1];
    const float* bias = (const float*)d_in[2];
    float* out        = (float*)d_out;

    dim3 grid(NF * CHUNKS);   // 1024
    dim3 block(256);
    nlinear_kernel<<<grid, block, 0, stream>>>(x, wght, bias, out);
}